// Round 3
// baseline (118.157 us; speedup 1.0000x reference)
//
#include <hip/hip_runtime.h>

namespace {
constexpr int kNP = 8, kNR = 12;
constexpr int kRelCell = 288;          // NP*K*NR floats per (b,v,f,t) cell
constexpr int kH = 64, kNOUT = 64;
constexpr int CELLS  = 4;              // cells per wave
constexpr int WAVES  = 4;
constexpr int CHUNKS = 16;             // blocks per (b,v); block covers f=chunk, t=0..15
constexpr int WT_LD  = 65;             // padded leading dim: conflict-free
constexpr int RELW   = kRelCell * CELLS; // 1152 floats (4608 B) per wave
}

__device__ __forceinline__ float readlane_f(float v, int l) {
    union { float f; int i; } u; u.f = v;
    u.i = __builtin_amdgcn_readlane(u.i, l);
    return u.f;
}

// async global->LDS, 16 B per lane; LDS dest = uniform base + lane*16
__device__ __forceinline__ void gll16(const float* g, float* l) {
    __builtin_amdgcn_global_load_lds(
        (const __attribute__((address_space(1))) void*)g,
        (__attribute__((address_space(3))) void*)l, 16, 0, 0);
}
// async global->LDS, 4 B per lane
__device__ __forceinline__ void gll4(const float* g, float* l) {
    __builtin_amdgcn_global_load_lds(
        (const __attribute__((address_space(1))) void*)g,
        (__attribute__((address_space(3))) void*)l, 4, 0, 0);
}

// grid: 128 (b,v) * 16 chunks = 2048 blocks of 256 threads (4 waves).
// Wave w owns cells (f=chunk, t=4w..4w+3): one contiguous 4.6 KB rel stream,
// staged upfront with 6 async global_load_lds (zero VGPR cost).
__global__ __launch_bounds__(256, 4) void gal_kernel(
    const float* __restrict__ rel,      // (BS,NV,MF,MT,NP,K,NR)
    const float* __restrict__ se,       // (BS,NV,MT,MF,H)
    const float* __restrict__ s,        // (BS,NV,NOUT)
    const float* __restrict__ Wstack,   // (NR,H,H)
    const float* __restrict__ lin_w,    // (1,H+NOUT)
    const float* __restrict__ lin_b,    // (1,)
    const float* __restrict__ out_w,    // (NOUT,H)
    const float* __restrict__ out_b,    // (NOUT,)
    float* __restrict__ out)            // (BS,NV,NOUT)
{
    __shared__ __align__(16) float wT[kH * WT_LD];        // 16.6 KB
    __shared__ __align__(16) float relbuf[WAVES][RELW];   // 18.4 KB
    __shared__ __align__(16) float redbuf[WAVES * 64];    // 1 KB

    const int tid  = (int)threadIdx.x;
    const int lane = tid & 63;
    const int w    = tid >> 6;

    const int bv    = (int)blockIdx.x >> 4;   // 0..127
    const int chunk = (int)blockIdx.x & 15;
    const int f  = chunk;
    const int t0 = w * CELLS;

    // ---- issue async rel staging FIRST (latency hides under constant setup)
    const float* relp = rel + ((size_t)(bv * 16 + f) * 16 + t0) * kRelCell;
    float* rb = &relbuf[w][0];
#pragma unroll
    for (int j = 0; j < 4; ++j)
        gll16(relp + j * 256 + lane * 4, rb + j * 256);   // 4 x 1024 B
    gll4(relp + 1024 + lane, rb + 1024);                  // tail 512 B
    gll4(relp + 1088 + lane, rb + 1088);

    // out_w (o,d) -> wT[d*65+o]; writes stride 65 -> conflict-free
    for (int i = tid; i < kH * kNOUT; i += 256) {
        const int o = i >> 6, d = i & 63;
        wT[d * WT_LD + o] = out_w[i];
    }

    // se values for the wave's 4 cells (lane = d)
    const float* sep = se + ((size_t)(bv * 16 + t0) * 16 + f) * kH + lane;
    float sev[CELLS];
#pragma unroll
    for (int i = 0; i < CELLS; ++i) sev[i] = sep[(size_t)i * (16 * kH)];

    // lane = d constants
    float dreg[kNR];
#pragma unroll
    for (int r = 0; r < kNR; ++r)
        dreg[r] = Wstack[r * kH * kH + lane * (kH + 1)];
    const float wz = lin_w[kNOUT + lane];
    float sv = s[bv * kNOUT + lane] * lin_w[lane];
#pragma unroll
    for (int m = 1; m < 64; m <<= 1) sv += __shfl_xor(sv, m, 64);
    const float logit_base = sv + lin_b[0];
    const float ob = out_b[lane];   // lane = o in epilogue

    // barrier: wT ready AND (compiler-emitted vmcnt(0) drain) rel staging done
    __syncthreads();

    float zreg[CELLS];
#pragma unroll
    for (int i = 0; i < CELLS; ++i) {
        const float* cb = rb + i * kRelCell;
        const float sv_i = sev[i];
        float zj[kNP], lg[kNP];
#pragma unroll
        for (int p = 0; p < kNP; ++p) {
            const float4* r4 = (const float4*)(cb + p * 36);  // broadcast reads
            const float4 a0 = r4[0], a1 = r4[1], a2 = r4[2];
            const float4 b0 = r4[3], b1 = r4[4], b2 = r4[5];
            const float4 c0 = r4[6], c1 = r4[7], c2 = r4[8];
            float d0 = a0.x*dreg[0] + a0.y*dreg[1] + a0.z*dreg[2] + a0.w*dreg[3]
                     + a1.x*dreg[4] + a1.y*dreg[5] + a1.z*dreg[6] + a1.w*dreg[7]
                     + a2.x*dreg[8] + a2.y*dreg[9] + a2.z*dreg[10] + a2.w*dreg[11];
            float d1 = b0.x*dreg[0] + b0.y*dreg[1] + b0.z*dreg[2] + b0.w*dreg[3]
                     + b1.x*dreg[4] + b1.y*dreg[5] + b1.z*dreg[6] + b1.w*dreg[7]
                     + b2.x*dreg[8] + b2.y*dreg[9] + b2.z*dreg[10] + b2.w*dreg[11];
            float d2 = c0.x*dreg[0] + c0.y*dreg[1] + c0.z*dreg[2] + c0.w*dreg[3]
                     + c1.x*dreg[4] + c1.y*dreg[5] + c1.z*dreg[6] + c1.w*dreg[7]
                     + c2.x*dreg[8] + c2.y*dreg[9] + c2.z*dreg[10] + c2.w*dreg[11];
            const float z = d0 * d1 * d2 * sv_i;
            zj[p] = z;
            float la = z * wz;
#pragma unroll
            for (int m = 1; m < 64; m <<= 1) la += __shfl_xor(la, m, 64);
            lg[p] = la + logit_base;
        }

        // softmax over p (identical in all lanes)
        float mx = lg[0];
#pragma unroll
        for (int p = 1; p < kNP; ++p) mx = fmaxf(mx, lg[p]);
        float esum = 0.f, zd = 0.f;
        float e[kNP];
#pragma unroll
        for (int p = 0; p < kNP; ++p) { e[p] = __expf(lg[p] - mx); esum += e[p]; }
        const float inv = 1.0f / esum;
#pragma unroll
        for (int p = 0; p < kNP; ++p) zd = fmaf(e[p] * inv, zj[p], zd);
        zreg[i] = zd;
    }

    // batched 64x64 matvec for the wave's 4 cells; lane = o
    float q[CELLS];
#pragma unroll
    for (int i = 0; i < CELLS; ++i) q[i] = 0.f;
#pragma unroll
    for (int d = 0; d < kH; ++d) {
        const float wv = wT[d * WT_LD + lane];
#pragma unroll
        for (int i = 0; i < CELLS; ++i)
            q[i] = fmaf(readlane_f(zreg[i], d), wv, q[i]);
    }
    float tot = 0.f;
#pragma unroll
    for (int i = 0; i < CELLS; ++i) tot += fmaxf(q[i] + ob, 0.f);

    // block-level reduce -> single wave-atomic per block
    __syncthreads();
    redbuf[w * 64 + lane] = tot;
    __syncthreads();
    if (w == 0) {
        const float r = redbuf[lane] + redbuf[64 + lane]
                      + redbuf[128 + lane] + redbuf[192 + lane];
        atomicAdd(&out[bv * kNOUT + lane], r);
    }
}

extern "C" void kernel_launch(void* const* d_in, const int* in_sizes, int n_in,
                              void* d_out, int out_size, void* d_ws, size_t ws_size,
                              hipStream_t stream) {
    const float* rel   = (const float*)d_in[0];
    const float* sem   = (const float*)d_in[1];
    const float* s     = (const float*)d_in[2];
    const float* Wst   = (const float*)d_in[3];
    const float* lin_w = (const float*)d_in[4];
    const float* lin_b = (const float*)d_in[5];
    const float* out_w = (const float*)d_in[6];
    const float* out_b = (const float*)d_in[7];
    float* out = (float*)d_out;

    hipMemsetAsync(out, 0, sizeof(float) * 8 * 16 * kNOUT, stream);
    dim3 grid(8 * 16 * CHUNKS), block(256);
    hipLaunchKernelGGL(gal_kernel, grid, block, 0, stream,
                       rel, sem, s, Wst, lin_w, lin_b, out_w, out_b, out);
}

// Round 4
// 80.827 us; speedup vs baseline: 1.4618x; 1.4618x over previous
//
#include <hip/hip_runtime.h>

namespace {
constexpr int kNP = 8, kNR = 12;
constexpr int kRelCell = 288;          // NP*K*NR floats per (b,v,f,t) cell
constexpr int kH = 64, kNOUT = 64;
constexpr int CELLS  = 4;              // cells per wave
constexpr int WAVES  = 4;
constexpr int CHUNKS = 16;             // blocks per (b,v); block covers f=chunk, t=0..15
constexpr int WT_LD  = 65;             // padded leading dim: conflict-free
constexpr int RELW   = kRelCell * CELLS; // 1152 floats (4608 B) per wave
}

__device__ __forceinline__ float readlane_f(float v, int l) {
    union { float f; int i; } u; u.f = v;
    u.i = __builtin_amdgcn_readlane(u.i, l);
    return u.f;
}

// async global->LDS, 16 B per lane; LDS dest = uniform base + lane*16
__device__ __forceinline__ void gll16(const float* g, float* l) {
    __builtin_amdgcn_global_load_lds(
        (const __attribute__((address_space(1))) void*)g,
        (__attribute__((address_space(3))) void*)l, 16, 0, 0);
}
// async global->LDS, 4 B per lane
__device__ __forceinline__ void gll4(const float* g, float* l) {
    __builtin_amdgcn_global_load_lds(
        (const __attribute__((address_space(1))) void*)g,
        (__attribute__((address_space(3))) void*)l, 4, 0, 0);
}

// grid: 128 (b,v) * 16 chunks = 2048 blocks of 256 threads (4 waves).
// Wave w owns cells (f=chunk, t=4w..4w+3): one contiguous 4.6 KB rel stream,
// staged upfront with 6 async global_load_lds (zero VGPR cost).
// Online softmax over p keeps per-thread live state under the 64-VGPR budget
// (rounds 1-3 spilled: WRITE_SIZE 35/121/212 MB of scratch traffic).
__global__ __launch_bounds__(256, 2) void gal_kernel(
    const float* __restrict__ rel,      // (BS,NV,MF,MT,NP,K,NR)
    const float* __restrict__ se,       // (BS,NV,MT,MF,H)
    const float* __restrict__ s,        // (BS,NV,NOUT)
    const float* __restrict__ Wstack,   // (NR,H,H)
    const float* __restrict__ lin_w,    // (1,H+NOUT)
    const float* __restrict__ lin_b,    // (1,)
    const float* __restrict__ out_w,    // (NOUT,H)
    const float* __restrict__ out_b,    // (NOUT,)
    float* __restrict__ out)            // (BS,NV,NOUT)
{
    __shared__ __align__(16) float wT[kH * WT_LD];        // 16.6 KB
    __shared__ __align__(16) float relbuf[WAVES][RELW];   // 18.4 KB
    __shared__ __align__(16) float redbuf[WAVES * 64];    // 1 KB

    const int tid  = (int)threadIdx.x;
    const int lane = tid & 63;
    const int w    = tid >> 6;

    const int bv    = (int)blockIdx.x >> 4;   // 0..127
    const int chunk = (int)blockIdx.x & 15;
    const int f  = chunk;
    const int t0 = w * CELLS;

    // ---- issue async rel staging FIRST (latency hides under constant setup)
    const float* relp = rel + ((size_t)(bv * 16 + f) * 16 + t0) * kRelCell;
    float* rb = &relbuf[w][0];
#pragma unroll
    for (int j = 0; j < 4; ++j)
        gll16(relp + j * 256 + lane * 4, rb + j * 256);   // 4 x 1024 B
    gll4(relp + 1024 + lane, rb + 1024);                  // tail 512 B
    gll4(relp + 1088 + lane, rb + 1088);

    // out_w (o,d) -> wT[d*65+o]; writes stride 65 -> conflict-free
    for (int i = tid; i < kH * kNOUT; i += 256) {
        const int o = i >> 6, d = i & 63;
        wT[d * WT_LD + o] = out_w[i];
    }

    // se values for the wave's 4 cells (lane = d)
    const float* sep = se + ((size_t)(bv * 16 + t0) * 16 + f) * kH + lane;
    float sev[CELLS];
#pragma unroll
    for (int i = 0; i < CELLS; ++i) sev[i] = sep[(size_t)i * (16 * kH)];

    // lane = d constants
    float dreg[kNR];
#pragma unroll
    for (int r = 0; r < kNR; ++r)
        dreg[r] = Wstack[r * kH * kH + lane * (kH + 1)];
    const float wz = lin_w[kNOUT + lane];
    float sv = s[bv * kNOUT + lane] * lin_w[lane];
#pragma unroll
    for (int m = 1; m < 64; m <<= 1) sv += __shfl_xor(sv, m, 64);
    const float logit_base = sv + lin_b[0];
    const float ob = out_b[lane];   // lane = o in epilogue

    // barrier: wT ready AND (compiler-emitted vmcnt(0) drain) rel staging done
    __syncthreads();

    float zreg[CELLS];
#pragma unroll
    for (int i = 0; i < CELLS; ++i) {
        const float* cb = rb + i * kRelCell;
        const float sv_i = sev[i];
        // online softmax state: mx/ssum wave-uniform, zacc per-lane
        float mx = -3.0e38f, ssum = 0.f, zacc = 0.f;
#pragma unroll
        for (int p = 0; p < kNP; ++p) {
            const float4* r4 = (const float4*)(cb + p * 36);  // broadcast reads
            const float4 a0 = r4[0], a1 = r4[1], a2 = r4[2];
            const float4 b0 = r4[3], b1 = r4[4], b2 = r4[5];
            const float4 c0 = r4[6], c1 = r4[7], c2 = r4[8];
            float d0 = a0.x*dreg[0] + a0.y*dreg[1] + a0.z*dreg[2] + a0.w*dreg[3]
                     + a1.x*dreg[4] + a1.y*dreg[5] + a1.z*dreg[6] + a1.w*dreg[7]
                     + a2.x*dreg[8] + a2.y*dreg[9] + a2.z*dreg[10] + a2.w*dreg[11];
            float d1 = b0.x*dreg[0] + b0.y*dreg[1] + b0.z*dreg[2] + b0.w*dreg[3]
                     + b1.x*dreg[4] + b1.y*dreg[5] + b1.z*dreg[6] + b1.w*dreg[7]
                     + b2.x*dreg[8] + b2.y*dreg[9] + b2.z*dreg[10] + b2.w*dreg[11];
            float d2 = c0.x*dreg[0] + c0.y*dreg[1] + c0.z*dreg[2] + c0.w*dreg[3]
                     + c1.x*dreg[4] + c1.y*dreg[5] + c1.z*dreg[6] + c1.w*dreg[7]
                     + c2.x*dreg[8] + c2.y*dreg[9] + c2.z*dreg[10] + c2.w*dreg[11];
            const float z = d0 * d1 * d2 * sv_i;
            float la = z * wz;
#pragma unroll
            for (int m = 1; m < 64; m <<= 1) la += __shfl_xor(la, m, 64);
            la += logit_base;
            // online update (la is lane-uniform)
            const float nm = fmaxf(mx, la);
            const float cs = __expf(mx - nm);   // 0 on first iter
            const float ep = __expf(la - nm);
            ssum = ssum * cs + ep;
            zacc = zacc * cs + ep * z;
            mx = nm;
        }
        zreg[i] = zacc / ssum;
    }

    // batched 64x64 matvec for the wave's 4 cells; lane = o
    float q[CELLS];
#pragma unroll
    for (int i = 0; i < CELLS; ++i) q[i] = 0.f;
#pragma unroll
    for (int d = 0; d < kH; ++d) {
        const float wv = wT[d * WT_LD + lane];
#pragma unroll
        for (int i = 0; i < CELLS; ++i)
            q[i] = fmaf(readlane_f(zreg[i], d), wv, q[i]);
    }
    float tot = 0.f;
#pragma unroll
    for (int i = 0; i < CELLS; ++i) tot += fmaxf(q[i] + ob, 0.f);

    // block-level reduce -> single wave-atomic per block
    __syncthreads();
    redbuf[w * 64 + lane] = tot;
    __syncthreads();
    if (w == 0) {
        const float r = redbuf[lane] + redbuf[64 + lane]
                      + redbuf[128 + lane] + redbuf[192 + lane];
        atomicAdd(&out[bv * kNOUT + lane], r);
    }
}

extern "C" void kernel_launch(void* const* d_in, const int* in_sizes, int n_in,
                              void* d_out, int out_size, void* d_ws, size_t ws_size,
                              hipStream_t stream) {
    const float* rel   = (const float*)d_in[0];
    const float* sem   = (const float*)d_in[1];
    const float* s     = (const float*)d_in[2];
    const float* Wst   = (const float*)d_in[3];
    const float* lin_w = (const float*)d_in[4];
    const float* lin_b = (const float*)d_in[5];
    const float* out_w = (const float*)d_in[6];
    const float* out_b = (const float*)d_in[7];
    float* out = (float*)d_out;

    hipMemsetAsync(out, 0, sizeof(float) * 8 * 16 * kNOUT, stream);
    dim3 grid(8 * 16 * CHUNKS), block(256);
    hipLaunchKernelGGL(gal_kernel, grid, block, 0, stream,
                       rel, sem, s, Wst, lin_w, lin_b, out_w, out_b, out);
}

// Round 5
// 67.449 us; speedup vs baseline: 1.7518x; 1.1983x over previous
//
#include <hip/hip_runtime.h>

namespace {
constexpr int kNP = 8, kNR = 12;
constexpr int kRelCell = 288;          // NP*K*NR floats per (b,v,f,t) cell
constexpr int kH = 64, kNOUT = 64;
constexpr int CELLS  = 4;              // cells per wave
constexpr int WAVES  = 4;
constexpr int CHUNKS = 16;             // blocks per (b,v); block = (f=chunk, t=0..15)
constexpr int WT_LD  = 65;             // padded leading dim: conflict-free
constexpr int RELW   = kRelCell * CELLS; // 1152 floats (4608 B) per wave
}

__device__ __forceinline__ float readlane_f(float v, int l) {
    union { float f; int i; } u; u.f = v;
    u.i = __builtin_amdgcn_readlane(u.i, l);
    return u.f;
}

// async global->LDS, 16 B per lane; LDS dest = uniform base + lane*16
__device__ __forceinline__ void gll16(const float* g, float* l) {
    __builtin_amdgcn_global_load_lds(
        (const __attribute__((address_space(1))) void*)g,
        (__attribute__((address_space(3))) void*)l, 16, 0, 0);
}
// async global->LDS, 4 B per lane
__device__ __forceinline__ void gll4(const float* g, float* l) {
    __builtin_amdgcn_global_load_lds(
        (const __attribute__((address_space(1))) void*)g,
        (__attribute__((address_space(3))) void*)l, 4, 0, 0);
}

// grid: 128 (b,v) * 16 chunks = 2048 blocks of 256 threads (4 waves).
// Wave w owns cells (f=chunk, t=4w..4w+3), rel staged via async global_load_lds.
// Batched (non-online) softmax: all 8 p-logits computed with full ILP, then
// 8 independent butterfly-reduce chains (round-4's online softmax serialized
// the whole cell into one ~2400-cycle dependency chain -> VALUBusy 33%).
// NOTE: s@w_s + lin_b is constant over p and cancels in softmax -> not computed.
__global__ __launch_bounds__(256, 2) void gal_kernel(
    const float* __restrict__ rel,      // (BS,NV,MF,MT,NP,K,NR)
    const float* __restrict__ se,       // (BS,NV,MT,MF,H)
    const float* __restrict__ s,        // (BS,NV,NOUT)    (unused: cancels)
    const float* __restrict__ Wstack,   // (NR,H,H)
    const float* __restrict__ lin_w,    // (1,H+NOUT)
    const float* __restrict__ lin_b,    // (1,)            (unused: cancels)
    const float* __restrict__ out_w,    // (NOUT,H)
    const float* __restrict__ out_b,    // (NOUT,)
    float* __restrict__ out)            // (BS,NV,NOUT)
{
    __shared__ __align__(16) float wT[kH * WT_LD];        // 16.6 KB
    __shared__ __align__(16) float relbuf[WAVES][RELW];   // 18.4 KB
    __shared__ __align__(16) float redbuf[WAVES * 64];    // 1 KB

    const int tid  = (int)threadIdx.x;
    const int lane = tid & 63;
    const int w    = tid >> 6;

    const int bv    = (int)blockIdx.x >> 4;   // 0..127
    const int f     = (int)blockIdx.x & 15;
    const int t0    = w * CELLS;

    // ---- issue async rel staging FIRST (latency hides under constant setup)
    const float* relp = rel + ((size_t)(bv * 16 + f) * 16 + t0) * kRelCell;
    float* rb = &relbuf[w][0];
#pragma unroll
    for (int j = 0; j < 4; ++j)
        gll16(relp + j * 256 + lane * 4, rb + j * 256);   // 4 x 1024 B
    gll4(relp + 1024 + lane, rb + 1024);                  // tail 512 B
    gll4(relp + 1088 + lane, rb + 1088);

    // out_w (o,d) -> wT[d*65+o]; stride-65 writes -> conflict-free
    for (int i = tid; i < kH * kNOUT; i += 256) {
        const int o = i >> 6, d = i & 63;
        wT[d * WT_LD + o] = out_w[i];
    }

    // se values for the wave's 4 cells (lane = d)
    const float* sep = se + ((size_t)(bv * 16 + t0) * 16 + f) * kH + lane;
    float sev[CELLS];
#pragma unroll
    for (int i = 0; i < CELLS; ++i) sev[i] = sep[(size_t)i * (16 * kH)];

    // lane = d constants
    float dreg[kNR];
#pragma unroll
    for (int r = 0; r < kNR; ++r)
        dreg[r] = Wstack[r * kH * kH + lane * (kH + 1)];
    const float wz = lin_w[kNOUT + lane];
    const float ob = out_b[lane];   // lane = o in epilogue

    // barrier: wT ready AND (compiler vmcnt(0) drain) rel staging complete
    __syncthreads();

    float zreg[CELLS];
#pragma unroll
    for (int i = 0; i < CELLS; ++i) {
        const float* cb = rb + i * kRelCell;
        const float sv_i = sev[i];
        float zj[kNP], lg[kNP];
        // phase 1: all 8 p-logit partials, fully independent (288 FMA of ILP)
#pragma unroll
        for (int p = 0; p < kNP; ++p) {
            const float4* r4 = (const float4*)(cb + p * 36);  // broadcast reads
            const float4 a0 = r4[0], a1 = r4[1], a2 = r4[2];
            const float4 b0 = r4[3], b1 = r4[4], b2 = r4[5];
            const float4 c0 = r4[6], c1 = r4[7], c2 = r4[8];
            float d0 = a0.x*dreg[0] + a0.y*dreg[1] + a0.z*dreg[2] + a0.w*dreg[3]
                     + a1.x*dreg[4] + a1.y*dreg[5] + a1.z*dreg[6] + a1.w*dreg[7]
                     + a2.x*dreg[8] + a2.y*dreg[9] + a2.z*dreg[10] + a2.w*dreg[11];
            float d1 = b0.x*dreg[0] + b0.y*dreg[1] + b0.z*dreg[2] + b0.w*dreg[3]
                     + b1.x*dreg[4] + b1.y*dreg[5] + b1.z*dreg[6] + b1.w*dreg[7]
                     + b2.x*dreg[8] + b2.y*dreg[9] + b2.z*dreg[10] + b2.w*dreg[11];
            float d2 = c0.x*dreg[0] + c0.y*dreg[1] + c0.z*dreg[2] + c0.w*dreg[3]
                     + c1.x*dreg[4] + c1.y*dreg[5] + c1.z*dreg[6] + c1.w*dreg[7]
                     + c2.x*dreg[8] + c2.y*dreg[9] + c2.z*dreg[10] + c2.w*dreg[11];
            const float z = d0 * d1 * d2 * sv_i;
            zj[p] = z;
            lg[p] = z * wz;
        }
        // phase 2: 8 butterfly reductions over d, pipelined (independent per p)
#pragma unroll
        for (int m = 1; m < 64; m <<= 1) {
#pragma unroll
            for (int p = 0; p < kNP; ++p)
                lg[p] += __shfl_xor(lg[p], m, 64);
        }
        // phase 3: flat softmax (uniform across lanes) + combine
        float mx = lg[0];
#pragma unroll
        for (int p = 1; p < kNP; ++p) mx = fmaxf(mx, lg[p]);
        float esum = 0.f, zd = 0.f;
#pragma unroll
        for (int p = 0; p < kNP; ++p) {
            const float e = __expf(lg[p] - mx);
            esum += e;
            zd = fmaf(e, zj[p], zd);
        }
        zreg[i] = zd / esum;
    }

    // batched 64x64 matvec for the wave's 4 cells; lane = o
    float q[CELLS];
#pragma unroll
    for (int i = 0; i < CELLS; ++i) q[i] = 0.f;
#pragma unroll
    for (int d = 0; d < kH; ++d) {
        const float wv = wT[d * WT_LD + lane];
#pragma unroll
        for (int i = 0; i < CELLS; ++i)
            q[i] = fmaf(readlane_f(zreg[i], d), wv, q[i]);
    }
    float tot = 0.f;
#pragma unroll
    for (int i = 0; i < CELLS; ++i) tot += fmaxf(q[i] + ob, 0.f);

    // block-level reduce -> single wave-atomic per block
    __syncthreads();
    redbuf[w * 64 + lane] = tot;
    __syncthreads();
    if (w == 0) {
        const float r = redbuf[lane] + redbuf[64 + lane]
                      + redbuf[128 + lane] + redbuf[192 + lane];
        atomicAdd(&out[bv * kNOUT + lane], r);
    }
}

extern "C" void kernel_launch(void* const* d_in, const int* in_sizes, int n_in,
                              void* d_out, int out_size, void* d_ws, size_t ws_size,
                              hipStream_t stream) {
    const float* rel   = (const float*)d_in[0];
    const float* sem   = (const float*)d_in[1];
    const float* s     = (const float*)d_in[2];
    const float* Wst   = (const float*)d_in[3];
    const float* lin_w = (const float*)d_in[4];
    const float* lin_b = (const float*)d_in[5];
    const float* out_w = (const float*)d_in[6];
    const float* out_b = (const float*)d_in[7];
    float* out = (float*)d_out;

    hipMemsetAsync(out, 0, sizeof(float) * 8 * 16 * kNOUT, stream);
    dim3 grid(8 * 16 * CHUNKS), block(256);
    hipLaunchKernelGGL(gal_kernel, grid, block, 0, stream,
                       rel, sem, s, Wst, lin_w, lin_b, out_w, out_b, out);
}

// Round 6
// 51.910 us; speedup vs baseline: 2.2762x; 1.2994x over previous
//
#include <hip/hip_runtime.h>

namespace {
constexpr int kNP = 8, kNR = 12;
constexpr int kRelCell = 288;              // NP*K*NR floats per cell
constexpr int kH = 64, kNOUT = 64;
constexpr int CELLS  = 8;                  // cells per wave (fixed f, 8 t's)
constexpr int GCELLS = 2;                  // cells per staged group
constexpr int NGRP   = CELLS / GCELLS;     // 4 groups, double-buffered
constexpr int GFLT   = kRelCell * GCELLS;  // 576 floats = 2304 B per group
constexpr int WAVES  = 4;
constexpr int WT_LD  = 65;                 // padded: conflict-free
}

__device__ __forceinline__ float readlane_f(float v, int l) {
    union { float f; int i; } u; u.f = v;
    u.i = __builtin_amdgcn_readlane(u.i, l);
    return u.f;
}

// DPP add step: x += dpp_mov(x); invalid source lanes contribute 0.
template<int CTRL>
__device__ __forceinline__ float dpp_add(float x) {
    int y = __builtin_amdgcn_update_dpp(0, __float_as_int(x), CTRL, 0xf, 0xf, true);
    return x + __int_as_float(y);
}
// 64-lane sum on the VALU pipe (no DS ops); lane 63 holds the total.
__device__ __forceinline__ float wave_sum63(float x) {
    x = dpp_add<0x111>(x);  // row_shr:1
    x = dpp_add<0x112>(x);  // row_shr:2
    x = dpp_add<0x114>(x);  // row_shr:4
    x = dpp_add<0x118>(x);  // row_shr:8
    x = dpp_add<0x142>(x);  // row_bcast:15
    x = dpp_add<0x143>(x);  // row_bcast:31
    return x;
}

// async global->LDS (LDS dest = uniform base + lane*width)
__device__ __forceinline__ void gll16(const float* g, float* l) {
    __builtin_amdgcn_global_load_lds(
        (const __attribute__((address_space(1))) void*)g,
        (__attribute__((address_space(3))) void*)l, 16, 0, 0);
}
__device__ __forceinline__ void gll4(const float* g, float* l) {
    __builtin_amdgcn_global_load_lds(
        (const __attribute__((address_space(1))) void*)g,
        (__attribute__((address_space(3))) void*)l, 4, 0, 0);
}
// stage one 2-cell group (2304 B) with 3 async ops
__device__ __forceinline__ void stage_group(const float* g, float* lds, int lane) {
    gll16(g + lane * 4, lds);                   // 1024 B
    gll16(g + 256 + lane * 4, lds + 256);       // 1024 B
    gll4 (g + 512 + lane, lds + 512);           // 256 B
}

#define VMWAIT3 asm volatile("s_waitcnt vmcnt(3)" ::: "memory")
#define VMWAIT0 asm volatile("s_waitcnt vmcnt(0)" ::: "memory")
#define LGKMWAIT0 asm volatile("s_waitcnt lgkmcnt(0)" ::: "memory")

// grid: 1024 blocks (4/CU) of 256 threads (4 waves). Wave Wid (0..31 per bv):
// f = Wid>>1, t = (Wid&1)*8 .. +7 -> 8 cells, rel stream contiguous 9.2 KB,
// staged in 4 double-buffered groups, per-wave vmcnt(3) pipeline, NO in-loop
// barriers (wave-private buffers). Softmax logit reduction on DPP/VALU pipe.
__global__ __launch_bounds__(256, 4) void gal_kernel(
    const float* __restrict__ rel,      // (BS,NV,MF,MT,NP,K,NR)
    const float* __restrict__ se,       // (BS,NV,MT,MF,H)
    const float* __restrict__ s,        // unused (cancels in softmax)
    const float* __restrict__ Wstack,   // (NR,H,H)
    const float* __restrict__ lin_w,    // (1,H+NOUT)
    const float* __restrict__ lin_b,    // unused (cancels)
    const float* __restrict__ out_w,    // (NOUT,H)
    const float* __restrict__ out_b,    // (NOUT,)
    float* __restrict__ out)            // (BS,NV,NOUT)
{
    __shared__ __align__(16) float wT[kH * WT_LD];            // 16.6 KB
    __shared__ __align__(16) float relbuf[WAVES][2][GFLT];    // 18.4 KB
    __shared__ __align__(16) float redbuf[WAVES * 64];        // 1 KB

    const int tid  = (int)threadIdx.x;
    const int lane = tid & 63;
    const int w    = tid >> 6;

    const int bv  = (int)blockIdx.x >> 3;      // 0..127
    const int sub = (int)blockIdx.x & 7;
    const int Wid = sub * 4 + w;               // 0..31 within bv
    const int f   = Wid >> 1;
    const int t0  = (Wid & 1) * 8;

    // ---- prologue loads (all VMEM issued before the drain) ----
    float dreg[kNR];
#pragma unroll
    for (int r = 0; r < kNR; ++r)
        dreg[r] = Wstack[r * kH * kH + lane * (kH + 1)];
    const float wz = lin_w[kNOUT + lane];
    const float ob = out_b[lane];

    const float* sep = se + ((size_t)(bv * 16 + t0) * 16 + f) * kH + lane;
    float sev[CELLS];
#pragma unroll
    for (int i = 0; i < CELLS; ++i) sev[i] = sep[(size_t)i * (16 * kH)];

    // out_w (o,d) -> wT[d*65 + o]; stride-65 writes are conflict-free
    for (int i = tid; i < kH * kNOUT; i += 256) {
        const int o = i >> 6, d = i & 63;
        wT[d * WT_LD + o] = out_w[i];
    }

    // drain prologue VMEM so in-loop vmcnt counts are exact
    VMWAIT0;
    __builtin_amdgcn_sched_barrier(0);

    // ---- prime the double-buffered staging pipeline ----
    const float* relbase = rel + ((size_t)(bv * 16 + f) * 16 + t0) * kRelCell;
    stage_group(relbase,        &relbuf[w][0][0], lane);
    stage_group(relbase + GFLT, &relbuf[w][1][0], lane);

    float zreg[CELLS];
#pragma unroll
    for (int g = 0; g < NGRP; ++g) {
        if (g < NGRP - 1) { VMWAIT3; } else { VMWAIT0; }   // group g landed

        const float* gb = &relbuf[w][g & 1][0];
#pragma unroll
        for (int c = 0; c < GCELLS; ++c) {
            const float* cb = gb + c * kRelCell;
            const float sv_i = sev[g * GCELLS + c];
            float zj[kNP], la[kNP];
#pragma unroll
            for (int p = 0; p < kNP; ++p) {
                const float4* r4 = (const float4*)(cb + p * 36);
                const float4 a0 = r4[0], a1 = r4[1], a2 = r4[2];
                const float4 b0 = r4[3], b1 = r4[4], b2 = r4[5];
                const float4 c0 = r4[6], c1 = r4[7], c2 = r4[8];
                float d0 = a0.x*dreg[0] + a0.y*dreg[1] + a0.z*dreg[2] + a0.w*dreg[3]
                         + a1.x*dreg[4] + a1.y*dreg[5] + a1.z*dreg[6] + a1.w*dreg[7]
                         + a2.x*dreg[8] + a2.y*dreg[9] + a2.z*dreg[10] + a2.w*dreg[11];
                float d1 = b0.x*dreg[0] + b0.y*dreg[1] + b0.z*dreg[2] + b0.w*dreg[3]
                         + b1.x*dreg[4] + b1.y*dreg[5] + b1.z*dreg[6] + b1.w*dreg[7]
                         + b2.x*dreg[8] + b2.y*dreg[9] + b2.z*dreg[10] + b2.w*dreg[11];
                float d2 = c0.x*dreg[0] + c0.y*dreg[1] + c0.z*dreg[2] + c0.w*dreg[3]
                         + c1.x*dreg[4] + c1.y*dreg[5] + c1.z*dreg[6] + c1.w*dreg[7]
                         + c2.x*dreg[8] + c2.y*dreg[9] + c2.z*dreg[10] + c2.w*dreg[11];
                const float z = d0 * d1 * d2 * sv_i;
                zj[p] = z;
                la[p] = z * wz;
            }
            // 8 independent 64-lane sums on the VALU pipe (DPP)
#pragma unroll
            for (int p = 0; p < kNP; ++p) la[p] = wave_sum63(la[p]);
            float lg[kNP];
#pragma unroll
            for (int p = 0; p < kNP; ++p) lg[p] = readlane_f(la[p], 63);
            // flat softmax (uniform) + combine
            float mx = lg[0];
#pragma unroll
            for (int p = 1; p < kNP; ++p) mx = fmaxf(mx, lg[p]);
            float esum = 0.f, zd = 0.f;
#pragma unroll
            for (int p = 0; p < kNP; ++p) {
                const float e = __expf(lg[p] - mx);
                esum += e;
                zd = fmaf(e, zj[p], zd);
            }
            zreg[g * GCELLS + c] = zd / esum;
        }

        if (g + 2 < NGRP) {
            LGKMWAIT0;  // this group's ds_reads retired before overwrite
            stage_group(relbase + (size_t)(g + 2) * GFLT, &relbuf[w][g & 1][0], lane);
        }
    }

    // ---- epilogue: batched 64x64 matvec over 8 cells; lane = o ----
    __syncthreads();  // wT ready (only barrier before reduction)
    float q[CELLS];
#pragma unroll
    for (int i = 0; i < CELLS; ++i) q[i] = 0.f;
#pragma unroll
    for (int d = 0; d < kH; ++d) {
        const float wv = wT[d * WT_LD + lane];
#pragma unroll
        for (int i = 0; i < CELLS; ++i)
            q[i] = fmaf(readlane_f(zreg[i], d), wv, q[i]);
    }
    float tot = 0.f;
#pragma unroll
    for (int i = 0; i < CELLS; ++i) tot += fmaxf(q[i] + ob, 0.f);

    // block reduce -> one wave-atomic per block
    redbuf[w * 64 + lane] = tot;
    __syncthreads();
    if (w == 0) {
        const float r = redbuf[lane] + redbuf[64 + lane]
                      + redbuf[128 + lane] + redbuf[192 + lane];
        atomicAdd(&out[bv * kNOUT + lane], r);
    }
}

extern "C" void kernel_launch(void* const* d_in, const int* in_sizes, int n_in,
                              void* d_out, int out_size, void* d_ws, size_t ws_size,
                              hipStream_t stream) {
    const float* rel   = (const float*)d_in[0];
    const float* sem   = (const float*)d_in[1];
    const float* s     = (const float*)d_in[2];
    const float* Wst   = (const float*)d_in[3];
    const float* lin_w = (const float*)d_in[4];
    const float* lin_b = (const float*)d_in[5];
    const float* out_w = (const float*)d_in[6];
    const float* out_b = (const float*)d_in[7];
    float* out = (float*)d_out;

    hipMemsetAsync(out, 0, sizeof(float) * 8 * 16 * kNOUT, stream);
    dim3 grid(1024), block(256);
    hipLaunchKernelGGL(gal_kernel, grid, block, 0, stream,
                       rel, sem, s, Wst, lin_w, lin_b, out_w, out_b, out);
}